// Round 9
// baseline (669.175 us; speedup 1.0000x reference)
//
#include <hip/hip_runtime.h>
#include <hip/hip_bf16.h>
#include <cstdint>
#include <cstddef>

typedef __hip_bfloat16 bf16;
typedef __attribute__((ext_vector_type(8))) short short8;
typedef __attribute__((ext_vector_type(4))) float floatx4;
typedef __attribute__((ext_vector_type(16))) float floatx16;
typedef __attribute__((ext_vector_type(8))) _Float16 half8;

#define Bsz 16
#define Lseq 4096
#define Hd 256
#define NM 32          // complex modes per channel
#define NCH 16         // chunks
#define TCH 256        // chunk length (NCH*TCH == Lseq)
#define Mtot (Bsz*Lseq)

__device__ __forceinline__ float gelu_tanh(float y) {
  float y2 = y * y;
  float q = fmaf(0.044715f, y2, 1.0f);
  float a = 1.5957691216057308f * y * q;
  float e = __expf(-a);
  return y * __frcp_rn(1.0f + e);
}

// ---------------- K_prep: per-(dir,d) tables for the matmul formulation ---
// KK[dir][d][512]  fp16: dir0: KK[i]=K[255-i] (i<=255) else 0  (A[t][tau]=KK[255-t+tau])
//                        dir1: KK[i]=K[i-255] (i>=255) else 0
// Vm[dir][d][n2][256] fp16: dir0: Vm[2n][tau]=Re(w^{255-tau}) ; dir1: Re(w^{tau})
// P [dir][d][256][64] fp16: dir0: P[t][2n]=Re(C w^{t+1}), [2n+1]=-Im(C w^{t+1})
//                           dir1: exponent 256-t
// wtb[dir][d][64] fp32: [2n]=Re(w^256), [2n+1]=Im(w^256)
__global__ __launch_bounds__(64) void k_prep(
    const float* __restrict__ ldt_fw, const float* __restrict__ lar_fw,
    const float* __restrict__ ai_fw,  const float* __restrict__ C_fw,
    const float* __restrict__ ldt_bw, const float* __restrict__ lar_bw,
    const float* __restrict__ ai_bw,  const float* __restrict__ C_bw,
    _Float16* __restrict__ Vm, _Float16* __restrict__ P,
    _Float16* __restrict__ KK, float* __restrict__ wtb) {
  const int d = blockIdx.x, dir = blockIdx.y;
  const int lane = threadIdx.x;
  const int n = lane & 31;
  const bool active = lane < 32;
  const float* ldt = dir ? ldt_bw : ldt_fw;
  const float* lar = dir ? lar_bw : lar_fw;
  const float* ai  = dir ? ai_bw  : ai_fw;
  const float* C   = dir ? C_bw   : C_fw;

  float dt = expf(ldt[d]);
  float Ar = -expf(lar[d * NM + n]);
  float Ai = ai[d * NM + n];
  float c0 = C[(d * NM + n) * 2 + 0];
  float c1 = C[(d * NM + n) * 2 + 1];

  float er = expf(Ar * dt);
  float sn, cs;
  sincosf(Ai * dt, &sn, &cs);
  float wr = er * cs, wi = er * sn;
  // Ceff = 2*Cc*(w-1)/(A+1e-8)
  float nr = wr - 1.f, ni = wi;
  float tr_ = c0 * nr - c1 * ni;
  float ti  = c0 * ni + c1 * nr;
  float dr = Ar + 1e-8f, di = Ai;
  float inv = 1.f / (dr * dr + di * di);
  float Cr = 2.f * (tr_ * dr + ti * di) * inv;
  float Ci = 2.f * (ti * dr - tr_ * di) * inv;
  // wT = w^256 (direct exp for accuracy)
  float erT = expf(256.f * Ar * dt);
  float snT, csT;
  sincosf(256.f * Ai * dt, &snT, &csT);
  if (active) {
    wtb[(dir * 256 + d) * 64 + 2 * n]     = erT * csT;
    wtb[(dir * 256 + d) * 64 + 2 * n + 1] = erT * snT;
  }
  // zero KK
  _Float16* kk = KK + (dir * 256 + d) * 512;
  for (int i = lane; i < 512; i += 64) kk[i] = (_Float16)0.f;
  __syncthreads();

  _Float16* vm = Vm + (size_t)(dir * 256 + d) * 64 * 256;
  _Float16* pp = P  + (size_t)(dir * 256 + d) * 256 * 64;
  float pr = 1.f, pi = 0.f;  // w^j
  for (int j = 0; j <= 256; ++j) {
    float kc = active ? (Cr * pr - Ci * pi) : 0.f;
#pragma unroll
    for (int off = 32; off > 0; off >>= 1) kc += __shfl_xor(kc, off);
    if (lane == 0 && j <= 255) {
      int i = dir ? (255 + j) : (255 - j);
      kk[i] = (_Float16)kc;
    }
    if (active) {
      if (j <= 255) {
        int tv = dir ? j : (255 - j);
        vm[(2 * n) * 256 + tv]     = (_Float16)pr;
        vm[(2 * n + 1) * 256 + tv] = (_Float16)pi;
      }
      if (j >= 1) {
        int t = dir ? (256 - j) : (j - 1);
        float cwr = Cr * pr - Ci * pi;
        float cwi = Cr * pi + Ci * pr;
        pp[t * 64 + 2 * n]     = (_Float16)cwr;
        pp[t * 64 + 2 * n + 1] = (_Float16)(-cwi);
      }
    }
    float npr = pr * wr - pi * wi;
    float npi = pr * wi + pi * wr;
    pr = npr; pi = npi;
  }
}

// ---------------- K0b: conv_w fp32 -> bf16 ----------------
__global__ __launch_bounds__(256) void k_wconv(
    const float* __restrict__ W, bf16* __restrict__ Wb, int n) {
  int i = blockIdx.x * 256 + threadIdx.x;
  if (i < n) Wb[i] = __float2bfloat16(W[i]);
}

// ---------------- K_tr: x[m=b*L+l][d] fp32 -> x16[d][m] fp16 ------------
__global__ __launch_bounds__(256) void k_tr(
    const float* __restrict__ x, _Float16* __restrict__ x16) {
  __shared__ __align__(16) _Float16 t16[64][72];
  const int m0 = blockIdx.x * 64, d0 = blockIdx.y * 64;
  const int tid = threadIdx.x;
  {
    int li = tid >> 2, dq = (tid & 3) * 16;
    const float* src = x + (size_t)(m0 + li) * 256 + d0 + dq;
    float4 v0 = ((const float4*)src)[0];
    float4 v1 = ((const float4*)src)[1];
    float4 v2 = ((const float4*)src)[2];
    float4 v3 = ((const float4*)src)[3];
    half8 h0, h1;
    h0[0]=(_Float16)v0.x; h0[1]=(_Float16)v0.y; h0[2]=(_Float16)v0.z; h0[3]=(_Float16)v0.w;
    h0[4]=(_Float16)v1.x; h0[5]=(_Float16)v1.y; h0[6]=(_Float16)v1.z; h0[7]=(_Float16)v1.w;
    h1[0]=(_Float16)v2.x; h1[1]=(_Float16)v2.y; h1[2]=(_Float16)v2.z; h1[3]=(_Float16)v2.w;
    h1[4]=(_Float16)v3.x; h1[5]=(_Float16)v3.y; h1[6]=(_Float16)v3.z; h1[7]=(_Float16)v3.w;
    *(half8*)&t16[li][dq] = h0;
    *(half8*)&t16[li][dq + 8] = h1;
  }
  __syncthreads();
  {
    int dj = tid >> 2, lq = (tid & 3) * 16;
    half8 o0, o1;
#pragma unroll
    for (int i = 0; i < 8; ++i) {
      o0[i] = t16[lq + i][dj];
      o1[i] = t16[lq + 8 + i][dj];
    }
    _Float16* dst = x16 + (size_t)(d0 + dj) * 65536 + m0 + lq;
    ((half8*)dst)[0] = o0;
    ((half8*)dst)[1] = o1;
  }
}

// ---------------- K_mm1: chunk-local states L = Vm @ u ------------------
// one wg per (d, dir); 256 thr = 4 waves, wave wv owns 64 cols (col=b*16+c)
// Sloc_T layout: [b][dir][c][d][n2(64)] fp32
__global__ __launch_bounds__(256) void k_mm1(
    const _Float16* __restrict__ x16, const _Float16* __restrict__ Vm,
    float* __restrict__ Sloc) {
  const int d = blockIdx.x, dir = blockIdx.y;
  const int tid = threadIdx.x, lane = tid & 63, wv = tid >> 6;
  __shared__ __align__(16) _Float16 ub[256][24];  // 16 tau + 8 pad
  floatx16 acc[2][2];
#pragma unroll
  for (int a = 0; a < 2; ++a)
#pragma unroll
    for (int b = 0; b < 2; ++b)
#pragma unroll
      for (int i = 0; i < 16; ++i) acc[a][b][i] = 0.f;

  const _Float16* vmp = Vm + (size_t)(dir * 256 + d) * 64 * 256;
  const int arow = lane & 31, ak = (lane >> 5) * 8;
  const int colb = wv * 64;

  for (int ks = 0; ks < 16; ++ks) {
    const int tau0 = ks * 16;
    __syncthreads();
    {
      int col = tid;
      int b = col >> 4, c = col & 15;
      const _Float16* up = x16 + (size_t)d * 65536 + b * 4096 + c * 256 + tau0;
      ((int4*)&ub[col][0])[0] = ((const int4*)up)[0];
      ((int4*)&ub[col][0])[1] = ((const int4*)up)[1];
    }
    __syncthreads();
    half8 a0 = *(const half8*)(vmp + (size_t)(0 * 32 + arow) * 256 + tau0 + ak);
    half8 a1 = *(const half8*)(vmp + (size_t)(1 * 32 + arow) * 256 + tau0 + ak);
    half8 b0 = *(const half8*)&ub[colb + arow][ak];
    half8 b1 = *(const half8*)&ub[colb + 32 + arow][ak];
    acc[0][0] = __builtin_amdgcn_mfma_f32_32x32x16_f16(a0, b0, acc[0][0], 0, 0, 0);
    acc[0][1] = __builtin_amdgcn_mfma_f32_32x32x16_f16(a0, b1, acc[0][1], 0, 0, 0);
    acc[1][0] = __builtin_amdgcn_mfma_f32_32x32x16_f16(a1, b0, acc[1][0], 0, 0, 0);
    acc[1][1] = __builtin_amdgcn_mfma_f32_32x32x16_f16(a1, b1, acc[1][1], 0, 0, 0);
  }
  const int hi = lane >> 5;
#pragma unroll
  for (int rt = 0; rt < 2; ++rt)
#pragma unroll
    for (int ct = 0; ct < 2; ++ct) {
      int coll = colb + ct * 32 + (lane & 31);
      int b = coll >> 4, c = coll & 15;
      float* sp = Sloc + ((((size_t)(b * 2 + dir)) * 16 + c) * 256 + d) * 64;
#pragma unroll
      for (int r = 0; r < 16; r += 2) {
        int n2 = (r & 3) + 8 * (r >> 2) + 4 * hi + rt * 32;
        float2 v;
        v.x = acc[rt][ct][r];
        v.y = acc[rt][ct][r + 1];
        *(float2*)(sp + n2) = v;
      }
    }
}

// ---------------- K_scan2: cross-chunk prefix (in-place on Sloc_T) ------
// grid (Bsz, 2, 4): d = bz*64 + tid>>2, h = tid&3 owns modes [h*8,h*8+8)
// dir0: chunks 0..15 ; dir1: chunks 15..0 (spatial chunk index both dirs)
__global__ __launch_bounds__(256) void k_scan2(
    const float* __restrict__ wtb, float* __restrict__ S) {
  const int b = blockIdx.x, dir = blockIdx.y;
  const int d = blockIdx.z * 64 + (threadIdx.x >> 2), h = threadIdx.x & 3;
  const int nbase = h * 8;
  float wTr[8], wTi[8], sr[8], si[8];
  const float* wt = wtb + (dir * 256 + d) * 64;
#pragma unroll
  for (int n = 0; n < 8; ++n) {
    wTr[n] = wt[2 * (nbase + n)];
    wTi[n] = wt[2 * (nbase + n) + 1];
    sr[n] = 0.f; si[n] = 0.f;
  }
  for (int cc = 0; cc < NCH; ++cc) {
    int c = dir ? (NCH - 1 - cc) : cc;
    float* p = S + ((((size_t)(b * 2 + dir)) * 16 + c) * 256 + d) * 64;
#pragma unroll
    for (int n = 0; n < 8; ++n) {
      int n2 = 2 * (nbase + n);
      float lr = p[n2], li = p[n2 + 1];
      p[n2] = sr[n]; p[n2 + 1] = si[n];
      float t0  = fmaf(wTr[n], sr[n], lr);
      float nsr = fmaf(-wTi[n], si[n], t0);
      float nsi = fmaf(wTr[n], si[n], li);
      nsi = fmaf(wTi[n], sr[n], nsi);
      sr[n] = nsr; si[n] = nsi;
    }
  }
}

// ---------------- K_mm2: Y = Toeplitz(K)@u + P@S + Dk*u, GELU -> ActT ---
// one wg per (d, dir); 512 thr = 8 waves; wave wv owns t rows [wv*32,+32)
// ActT layout: [ch = dir*256+d][m = b*4096 + c*256 + t] bf16
__global__ __launch_bounds__(512) void k_mm2(
    const _Float16* __restrict__ x16, const _Float16* __restrict__ KK,
    const _Float16* __restrict__ P, const float* __restrict__ Sstart,
    const float* __restrict__ Dskip, bf16* __restrict__ ActT) {
  const int d = blockIdx.x, dir = blockIdx.y;
  const int tid = threadIdx.x, lane = tid & 63, wv = tid >> 6;
  __shared__ __align__(16) _Float16 ub[64][272];   // [col][256 tau + 16 pad]
  __shared__ __align__(16) _Float16 sb[64][72];    // [col][64 n2 + 8 pad]
  __shared__ __align__(16) _Float16 kks[8][520];   // 8 shifted copies

  // stage shifted KK copies: kks[r][x] = KK[x+r] (zero-padded)
  {
    const _Float16* kg = KK + (dir * 256 + d) * 512;
#pragma unroll
    for (int rr = 0; rr < 8; ++rr)
      for (int xx = tid; xx < 520; xx += 512) {
        int s = xx + rr;
        kks[rr][xx] = (s < 512) ? kg[s] : (_Float16)0.f;
      }
  }
  const float Dk = Dskip[d];
  const int t = wv * 32 + (lane & 31);
  const int hi = lane >> 5;
  const int r_sh = (255 - t) & 7;
  const _Float16* pp = P + (size_t)(dir * 256 + d) * 256 * 64 + (size_t)t * 64;

  for (int cb = 0; cb < 4; ++cb) {
    __syncthreads();
    {  // stage u: 64 cols x 256 tau (32 halves = 4 x int4 per (col,part))
      int col = tid >> 3, part = tid & 7;
      int coll = cb * 64 + col;
      int b = coll >> 4, c = coll & 15;
      const _Float16* up = x16 + (size_t)d * 65536 + b * 4096 + c * 256 + part * 32;
      ((int4*)&ub[col][part * 32])[0] = ((const int4*)up)[0];
      ((int4*)&ub[col][part * 32])[1] = ((const int4*)up)[1];
      ((int4*)&ub[col][part * 32])[2] = ((const int4*)up)[2];
      ((int4*)&ub[col][part * 32])[3] = ((const int4*)up)[3];
    }
    {  // stage S: 64 cols x 64 n2 (fp32 -> fp16)
      int col = tid >> 3, part = tid & 7;
      int coll = cb * 64 + col;
      int b = coll >> 4, c = coll & 15;
      const float* sp = Sstart + ((((size_t)(b * 2 + dir)) * 16 + c) * 256 + d) * 64 + part * 8;
      float4 f0 = ((const float4*)sp)[0];
      float4 f1 = ((const float4*)sp)[1];
      half8 hv;
      hv[0]=(_Float16)f0.x; hv[1]=(_Float16)f0.y; hv[2]=(_Float16)f0.z; hv[3]=(_Float16)f0.w;
      hv[4]=(_Float16)f1.x; hv[5]=(_Float16)f1.y; hv[6]=(_Float16)f1.z; hv[7]=(_Float16)f1.w;
      *(half8*)&sb[col][part * 8] = hv;
    }
    __syncthreads();

    floatx16 acc0, acc1;
#pragma unroll
    for (int i = 0; i < 16; ++i) { acc0[i] = 0.f; acc1[i] = 0.f; }

    // conv: Y += Toeplitz @ u   (A[t][tau] = KK[255 - t + tau])
#pragma unroll
    for (int ks = 0; ks < 16; ++ks) {
      int i0 = 255 - t + ks * 16 + hi * 8;
      half8 af = *(const half8*)&kks[r_sh][i0 - r_sh];
      half8 b0 = *(const half8*)&ub[(lane & 31)][ks * 16 + hi * 8];
      half8 b1 = *(const half8*)&ub[32 + (lane & 31)][ks * 16 + hi * 8];
      acc0 = __builtin_amdgcn_mfma_f32_32x32x16_f16(af, b0, acc0, 0, 0, 0);
      acc1 = __builtin_amdgcn_mfma_f32_32x32x16_f16(af, b1, acc1, 0, 0, 0);
    }
    // boundary: Y += P @ S
#pragma unroll
    for (int ks = 0; ks < 4; ++ks) {
      half8 af = *(const half8*)(pp + ks * 16 + hi * 8);
      half8 b0 = *(const half8*)&sb[(lane & 31)][ks * 16 + hi * 8];
      half8 b1 = *(const half8*)&sb[32 + (lane & 31)][ks * 16 + hi * 8];
      acc0 = __builtin_amdgcn_mfma_f32_32x32x16_f16(af, b0, acc0, 0, 0, 0);
      acc1 = __builtin_amdgcn_mfma_f32_32x32x16_f16(af, b1, acc1, 0, 0, 0);
    }
    // epilogue: skip + gelu -> ActT (packed 2x bf16 per dword store)
#pragma unroll
    for (int ct = 0; ct < 2; ++ct) {
      int coll = cb * 64 + ct * 32 + (lane & 31);
      int b = coll >> 4, c = coll & 15;
      bf16* op = ActT + (size_t)(dir * 256 + d) * 65536 + b * 4096 + c * 256;
      int ucol = ct * 32 + (lane & 31);
#pragma unroll
      for (int r = 0; r < 16; r += 2) {
        int tt = (r & 3) + 8 * (r >> 2) + 4 * hi + wv * 32;
        float a0 = (ct ? acc1[r] : acc0[r]);
        float a1 = (ct ? acc1[r + 1] : acc0[r + 1]);
        float u0 = (float)ub[ucol][tt];
        float u1 = (float)ub[ucol][tt + 1];
        float g0 = gelu_tanh(fmaf(u0, Dk, a0));
        float g1 = gelu_tanh(fmaf(u1, Dk, a1));
        bf16 h0 = __float2bfloat16(g0);
        bf16 h1 = __float2bfloat16(g1);
        unsigned pk = (unsigned)*(unsigned short*)&h0 |
                      ((unsigned)*(unsigned short*)&h1 << 16);
        *(unsigned*)(op + tt) = pk;
      }
    }
  }
}

// ---------------- K_tr2: ActT[ch][m] -> Act[m][ch] (bf16) ---------------
__global__ __launch_bounds__(256) void k_tr2(
    const bf16* __restrict__ AT, bf16* __restrict__ A) {
  __shared__ __align__(16) short tl[64][72];
  const int m0 = blockIdx.x * 64, ch0 = blockIdx.y * 64;
  const int tid = threadIdx.x;
  {
    int chi = tid >> 2, mq = (tid & 3) * 16;
    const short* src = (const short*)AT + (size_t)(ch0 + chi) * 65536 + m0 + mq;
    *(int4*)&tl[chi][mq] = ((const int4*)src)[0];
    *(int4*)&tl[chi][mq + 8] = ((const int4*)src)[1];
  }
  __syncthreads();
  {
    int mi = tid >> 2, chq = (tid & 3) * 16;
    short8 s0, s1;
#pragma unroll
    for (int i = 0; i < 8; ++i) {
      s0[i] = tl[chq + i][mi];
      s1[i] = tl[chq + 8 + i][mi];
    }
    short* dst = (short*)A + (size_t)(m0 + mi) * 512 + ch0 + chq;
    ((short8*)dst)[0] = s0;
    ((short8*)dst)[1] = s1;
  }
}

// ---------------- K4: GEMM (M,K=512)x(1024,K) + bias + GLU -> z ---------
// v4: LDS-free, barrier-free. Round-8 diagnosis: LDK=40 (20 dwords,
// gcd(20,32)=4) => 16 fragment rows land on 8 bank-groups => ~8-way LDS
// conflict (1.678e7 cycles), plus 32 barriers/block. MFMA fragment layout
// (row=lane&15, k=(lane>>4)*8) is directly loadable from row-major global:
// one wave b128 load = 16 rows x 64B = 16 full cache lines. Act/W are
// L2-resident (round-8 FETCH=41MB proves the XCD swizzle holds them).
// 16 independent acc chains give ILP; unroll-4 keeps loads in flight.
__global__ __launch_bounds__(256, 4) void k_gemm(
    const bf16* __restrict__ Act, const bf16* __restrict__ W,
    const float* __restrict__ bias, float* __restrict__ z) {
  const int id = blockIdx.x;
  const int x = id & 7, nj = (id >> 3) & 7, g = id >> 6;
  const int bi = g * 8 + x;
  const int tid = threadIdx.x, lane = tid & 63, wv = tid >> 6;
  const int wm = (wv & 1) * 64, wn = (wv >> 1) * 32;
  const int M0 = bi * 128, N0 = nj * 64;
  floatx4 acc_a[4][2], acc_g[4][2];
#pragma unroll
  for (int i = 0; i < 4; ++i)
#pragma unroll
    for (int j = 0; j < 2; ++j) {
      acc_a[i][j] = (floatx4){0.f, 0.f, 0.f, 0.f};
      acc_g[i][j] = (floatx4){0.f, 0.f, 0.f, 0.f};
    }
  const int fr = lane & 15, fk = (lane >> 4) * 8;

  const bf16* pA  = Act + (size_t)(M0 + wm + fr) * 512 + fk;
  const bf16* pBa = W + (size_t)(N0 + wn + fr) * 512 + fk;
  const bf16* pBg = W + (size_t)(512 + N0 + wn + fr) * 512 + fk;

#pragma unroll 4
  for (int kb = 0; kb < 512; kb += 32) {
    short8 af[4], bfa[2], bfg[2];
#pragma unroll
    for (int i = 0; i < 4; ++i)
      af[i] = *(const short8*)(pA + (size_t)(16 * i) * 512 + kb);
#pragma unroll
    for (int j = 0; j < 2; ++j) {
      bfa[j] = *(const short8*)(pBa + (size_t)(16 * j) * 512 + kb);
      bfg[j] = *(const short8*)(pBg + (size_t)(16 * j) * 512 + kb);
    }
#pragma unroll
    for (int i = 0; i < 4; ++i)
#pragma unroll
      for (int j = 0; j < 2; ++j) {
        acc_a[i][j] = __builtin_amdgcn_mfma_f32_16x16x32_bf16(af[i], bfa[j], acc_a[i][j], 0, 0, 0);
        acc_g[i][j] = __builtin_amdgcn_mfma_f32_16x16x32_bf16(af[i], bfg[j], acc_g[i][j], 0, 0, 0);
      }
  }
  // epilogue: bias + GLU, write z[m][o] fp32, o in [N0, N0+64)
  const int col = lane & 15, rquad = (lane >> 4) * 4;
#pragma unroll
  for (int j = 0; j < 2; ++j) {
    int o = N0 + wn + 16 * j + col;
    float ba = bias[o];
    float bg = bias[512 + o];
#pragma unroll
    for (int i = 0; i < 4; ++i) {
      int mbase = M0 + wm + 16 * i + rquad;
#pragma unroll
      for (int rg = 0; rg < 4; ++rg) {
        float a = acc_a[i][j][rg] + ba;
        float g = acc_g[i][j][rg] + bg;
        float zv = a * __frcp_rn(1.f + __expf(-g));
        z[(size_t)(mbase + rg) * 512 + o] = zv;
      }
    }
  }
}

// ---------------- K5: LayerNorm over 512 (in-place on d_out) ------------
__global__ __launch_bounds__(256) void k_ln(
    float* __restrict__ z, const float* __restrict__ gamma,
    const float* __restrict__ beta) {
  const int m = blockIdx.x * 4 + (threadIdx.x >> 6);
  const int lane = threadIdx.x & 63;
  float* zp = z + (size_t)m * 512;
  float v[8], s = 0.f, sq = 0.f;
#pragma unroll
  for (int j = 0; j < 8; ++j) {
    v[j] = zp[j * 64 + lane];
    s += v[j];
    sq = fmaf(v[j], v[j], sq);
  }
#pragma unroll
  for (int off = 32; off > 0; off >>= 1) {
    s += __shfl_xor(s, off);
    sq += __shfl_xor(sq, off);
  }
  float mean = s * (1.f / 512.f);
  float var = fmaf(-mean, mean, sq * (1.f / 512.f));
  float inv = rsqrtf(var + 1e-5f);
#pragma unroll
  for (int j = 0; j < 8; ++j) {
    int cidx = j * 64 + lane;
    float g = gamma[cidx], be = beta[cidx];
    zp[cidx] = fmaf((v[j] - mean) * inv, g, be);
  }
}

extern "C" void kernel_launch(void* const* d_in, const int* in_sizes, int n_in,
                              void* d_out, int out_size, void* d_ws, size_t ws_size,
                              hipStream_t stream) {
  const float* x      = (const float*)d_in[0];
  const float* ldt_fw = (const float*)d_in[1];
  const float* lar_fw = (const float*)d_in[2];
  const float* ai_fw  = (const float*)d_in[3];
  const float* C_fw   = (const float*)d_in[4];
  const float* ldt_bw = (const float*)d_in[5];
  const float* lar_bw = (const float*)d_in[6];
  const float* ai_bw  = (const float*)d_in[7];
  const float* C_bw   = (const float*)d_in[8];
  const float* Dskip  = (const float*)d_in[9];
  const float* W      = (const float*)d_in[10];
  const float* bias   = (const float*)d_in[11];
  const float* gamma  = (const float*)d_in[12];
  const float* beta   = (const float*)d_in[13];
  float* out = (float*)d_out;

  // workspace map (bytes):
  //  [0)          ActT   512*65536*2  = 67,108,864
  //  [67108864)   SlocT  16*2*16*256*64*4 = 33,554,432
  //  [100663296)  x16    256*65536*2  = 33,554,432
  //  [134217728)  Vm     2*256*64*256*2 = 16,777,216
  //  [150994944)  P      2*256*256*64*2 = 16,777,216
  //  [167772160)  KK     2*256*512*2  = 524,288
  //  [168296448)  wtb    2*256*64*4   = 131,072
  //  [168427520)  Wb     1,048,576     -> total ~169.5 MB
  //  Act (final [m][ch], 67,108,864 B) aliases [SlocT + x16]; both dead by k_tr2.
  char* wsb = (char*)d_ws;
  bf16*     ActT  = (bf16*)wsb;
  float*    SlocT = (float*)(wsb + 67108864u);
  _Float16* x16   = (_Float16*)(wsb + 100663296u);
  _Float16* Vm    = (_Float16*)(wsb + 134217728u);
  _Float16* P     = (_Float16*)(wsb + 150994944u);
  _Float16* KK    = (_Float16*)(wsb + 167772160u);
  float*    wtb   = (float*)(wsb + 168296448u);
  bf16*     Wb    = (bf16*)(wsb + 168427520u);
  bf16*     Act   = (bf16*)(wsb + 67108864u);   // alias over SlocT+x16

  k_prep<<<dim3(256, 2), dim3(64), 0, stream>>>(
      ldt_fw, lar_fw, ai_fw, C_fw, ldt_bw, lar_bw, ai_bw, C_bw, Vm, P, KK, wtb);
  k_wconv<<<dim3(2048), dim3(256), 0, stream>>>(W, Wb, 1024 * 512);
  k_tr<<<dim3(Mtot / 64, 4), dim3(256), 0, stream>>>(x, x16);
  k_mm1<<<dim3(256, 2), dim3(256), 0, stream>>>(x16, Vm, SlocT);
  k_scan2<<<dim3(Bsz, 2, 4), dim3(256), 0, stream>>>(wtb, SlocT);
  k_mm2<<<dim3(256, 2), dim3(512), 0, stream>>>(x16, KK, P, SlocT, Dskip, ActT);
  k_tr2<<<dim3(Mtot / 64, 8), dim3(256), 0, stream>>>(ActT, Act);
  k_gemm<<<dim3(4096), dim3(256), 0, stream>>>(Act, Wb, bias, out);
  k_ln<<<dim3(Mtot / 4), dim3(256), 0, stream>>>(out, gamma, beta);
}

// Round 10
// 557.797 us; speedup vs baseline: 1.1997x; 1.1997x over previous
//
#include <hip/hip_runtime.h>
#include <hip/hip_bf16.h>
#include <cstdint>
#include <cstddef>

typedef __hip_bfloat16 bf16;
typedef __attribute__((ext_vector_type(8))) short short8;
typedef __attribute__((ext_vector_type(4))) float floatx4;
typedef __attribute__((ext_vector_type(16))) float floatx16;
typedef __attribute__((ext_vector_type(8))) _Float16 half8;

#define Bsz 16
#define Lseq 4096
#define Hd 256
#define NM 32          // complex modes per channel
#define NCH 16         // chunks
#define TCH 256        // chunk length (NCH*TCH == Lseq)
#define Mtot (Bsz*Lseq)

__device__ __forceinline__ float gelu_tanh(float y) {
  float y2 = y * y;
  float q = fmaf(0.044715f, y2, 1.0f);
  float a = 1.5957691216057308f * y * q;
  float e = __expf(-a);
  return y * __frcp_rn(1.0f + e);
}

// ---------------- K_prep: per-(dir,d) tables for the matmul formulation ---
// KK[dir][d][512]  fp16: dir0: KK[i]=K[255-i] (i<=255) else 0  (A[t][tau]=KK[255-t+tau])
//                        dir1: KK[i]=K[i-255] (i>=255) else 0
// Vm[dir][d][n2][256] fp16: dir0: Vm[2n][tau]=Re(w^{255-tau}) ; dir1: Re(w^{tau})
// P [dir][d][256][64] fp16: dir0: P[t][2n]=Re(C w^{t+1}), [2n+1]=-Im(C w^{t+1})
//                           dir1: exponent 256-t
// wtb[dir][d][64] fp32: [2n]=Re(w^256), [2n+1]=Im(w^256)
__global__ __launch_bounds__(64) void k_prep(
    const float* __restrict__ ldt_fw, const float* __restrict__ lar_fw,
    const float* __restrict__ ai_fw,  const float* __restrict__ C_fw,
    const float* __restrict__ ldt_bw, const float* __restrict__ lar_bw,
    const float* __restrict__ ai_bw,  const float* __restrict__ C_bw,
    _Float16* __restrict__ Vm, _Float16* __restrict__ P,
    _Float16* __restrict__ KK, float* __restrict__ wtb) {
  const int d = blockIdx.x, dir = blockIdx.y;
  const int lane = threadIdx.x;
  const int n = lane & 31;
  const bool active = lane < 32;
  const float* ldt = dir ? ldt_bw : ldt_fw;
  const float* lar = dir ? lar_bw : lar_fw;
  const float* ai  = dir ? ai_bw  : ai_fw;
  const float* C   = dir ? C_bw   : C_fw;

  float dt = expf(ldt[d]);
  float Ar = -expf(lar[d * NM + n]);
  float Ai = ai[d * NM + n];
  float c0 = C[(d * NM + n) * 2 + 0];
  float c1 = C[(d * NM + n) * 2 + 1];

  float er = expf(Ar * dt);
  float sn, cs;
  sincosf(Ai * dt, &sn, &cs);
  float wr = er * cs, wi = er * sn;
  // Ceff = 2*Cc*(w-1)/(A+1e-8)
  float nr = wr - 1.f, ni = wi;
  float tr_ = c0 * nr - c1 * ni;
  float ti  = c0 * ni + c1 * nr;
  float dr = Ar + 1e-8f, di = Ai;
  float inv = 1.f / (dr * dr + di * di);
  float Cr = 2.f * (tr_ * dr + ti * di) * inv;
  float Ci = 2.f * (ti * dr - tr_ * di) * inv;
  // wT = w^256 (direct exp for accuracy)
  float erT = expf(256.f * Ar * dt);
  float snT, csT;
  sincosf(256.f * Ai * dt, &snT, &csT);
  if (active) {
    wtb[(dir * 256 + d) * 64 + 2 * n]     = erT * csT;
    wtb[(dir * 256 + d) * 64 + 2 * n + 1] = erT * snT;
  }
  // zero KK
  _Float16* kk = KK + (dir * 256 + d) * 512;
  for (int i = lane; i < 512; i += 64) kk[i] = (_Float16)0.f;
  __syncthreads();

  _Float16* vm = Vm + (size_t)(dir * 256 + d) * 64 * 256;
  _Float16* pp = P  + (size_t)(dir * 256 + d) * 256 * 64;
  float pr = 1.f, pi = 0.f;  // w^j
  for (int j = 0; j <= 256; ++j) {
    float kc = active ? (Cr * pr - Ci * pi) : 0.f;
#pragma unroll
    for (int off = 32; off > 0; off >>= 1) kc += __shfl_xor(kc, off);
    if (lane == 0 && j <= 255) {
      int i = dir ? (255 + j) : (255 - j);
      kk[i] = (_Float16)kc;
    }
    if (active) {
      if (j <= 255) {
        int tv = dir ? j : (255 - j);
        vm[(2 * n) * 256 + tv]     = (_Float16)pr;
        vm[(2 * n + 1) * 256 + tv] = (_Float16)pi;
      }
      if (j >= 1) {
        int t = dir ? (256 - j) : (j - 1);
        float cwr = Cr * pr - Ci * pi;
        float cwi = Cr * pi + Ci * pr;
        pp[t * 64 + 2 * n]     = (_Float16)cwr;
        pp[t * 64 + 2 * n + 1] = (_Float16)(-cwi);
      }
    }
    float npr = pr * wr - pi * wi;
    float npi = pr * wi + pi * wr;
    pr = npr; pi = npi;
  }
}

// ---------------- K0b: conv_w fp32 -> bf16 ----------------
__global__ __launch_bounds__(256) void k_wconv(
    const float* __restrict__ W, bf16* __restrict__ Wb, int n) {
  int i = blockIdx.x * 256 + threadIdx.x;
  if (i < n) Wb[i] = __float2bfloat16(W[i]);
}

// ---------------- K_tr: x[m=b*L+l][d] fp32 -> x16[d][m] fp16 ------------
__global__ __launch_bounds__(256) void k_tr(
    const float* __restrict__ x, _Float16* __restrict__ x16) {
  __shared__ __align__(16) _Float16 t16[64][72];
  const int m0 = blockIdx.x * 64, d0 = blockIdx.y * 64;
  const int tid = threadIdx.x;
  {
    int li = tid >> 2, dq = (tid & 3) * 16;
    const float* src = x + (size_t)(m0 + li) * 256 + d0 + dq;
    float4 v0 = ((const float4*)src)[0];
    float4 v1 = ((const float4*)src)[1];
    float4 v2 = ((const float4*)src)[2];
    float4 v3 = ((const float4*)src)[3];
    half8 h0, h1;
    h0[0]=(_Float16)v0.x; h0[1]=(_Float16)v0.y; h0[2]=(_Float16)v0.z; h0[3]=(_Float16)v0.w;
    h0[4]=(_Float16)v1.x; h0[5]=(_Float16)v1.y; h0[6]=(_Float16)v1.z; h0[7]=(_Float16)v1.w;
    h1[0]=(_Float16)v2.x; h1[1]=(_Float16)v2.y; h1[2]=(_Float16)v2.z; h1[3]=(_Float16)v2.w;
    h1[4]=(_Float16)v3.x; h1[5]=(_Float16)v3.y; h1[6]=(_Float16)v3.z; h1[7]=(_Float16)v3.w;
    *(half8*)&t16[li][dq] = h0;
    *(half8*)&t16[li][dq + 8] = h1;
  }
  __syncthreads();
  {
    int dj = tid >> 2, lq = (tid & 3) * 16;
    half8 o0, o1;
#pragma unroll
    for (int i = 0; i < 8; ++i) {
      o0[i] = t16[lq + i][dj];
      o1[i] = t16[lq + 8 + i][dj];
    }
    _Float16* dst = x16 + (size_t)(d0 + dj) * 65536 + m0 + lq;
    ((half8*)dst)[0] = o0;
    ((half8*)dst)[1] = o1;
  }
}

// ---------------- K_mm1: chunk-local states L = Vm @ u ------------------
// one wg per (d, dir); 256 thr = 4 waves, wave wv owns 64 cols (col=b*16+c)
// Sloc_T layout: [b][dir][c][d][n2(64)] fp32
__global__ __launch_bounds__(256) void k_mm1(
    const _Float16* __restrict__ x16, const _Float16* __restrict__ Vm,
    float* __restrict__ Sloc) {
  const int d = blockIdx.x, dir = blockIdx.y;
  const int tid = threadIdx.x, lane = tid & 63, wv = tid >> 6;
  __shared__ __align__(16) _Float16 ub[256][24];  // 16 tau + 8 pad
  floatx16 acc[2][2];
#pragma unroll
  for (int a = 0; a < 2; ++a)
#pragma unroll
    for (int b = 0; b < 2; ++b)
#pragma unroll
      for (int i = 0; i < 16; ++i) acc[a][b][i] = 0.f;

  const _Float16* vmp = Vm + (size_t)(dir * 256 + d) * 64 * 256;
  const int arow = lane & 31, ak = (lane >> 5) * 8;
  const int colb = wv * 64;

  for (int ks = 0; ks < 16; ++ks) {
    const int tau0 = ks * 16;
    __syncthreads();
    {
      int col = tid;
      int b = col >> 4, c = col & 15;
      const _Float16* up = x16 + (size_t)d * 65536 + b * 4096 + c * 256 + tau0;
      ((int4*)&ub[col][0])[0] = ((const int4*)up)[0];
      ((int4*)&ub[col][0])[1] = ((const int4*)up)[1];
    }
    __syncthreads();
    half8 a0 = *(const half8*)(vmp + (size_t)(0 * 32 + arow) * 256 + tau0 + ak);
    half8 a1 = *(const half8*)(vmp + (size_t)(1 * 32 + arow) * 256 + tau0 + ak);
    half8 b0 = *(const half8*)&ub[colb + arow][ak];
    half8 b1 = *(const half8*)&ub[colb + 32 + arow][ak];
    acc[0][0] = __builtin_amdgcn_mfma_f32_32x32x16_f16(a0, b0, acc[0][0], 0, 0, 0);
    acc[0][1] = __builtin_amdgcn_mfma_f32_32x32x16_f16(a0, b1, acc[0][1], 0, 0, 0);
    acc[1][0] = __builtin_amdgcn_mfma_f32_32x32x16_f16(a1, b0, acc[1][0], 0, 0, 0);
    acc[1][1] = __builtin_amdgcn_mfma_f32_32x32x16_f16(a1, b1, acc[1][1], 0, 0, 0);
  }
  const int hi = lane >> 5;
#pragma unroll
  for (int rt = 0; rt < 2; ++rt)
#pragma unroll
    for (int ct = 0; ct < 2; ++ct) {
      int coll = colb + ct * 32 + (lane & 31);
      int b = coll >> 4, c = coll & 15;
      float* sp = Sloc + ((((size_t)(b * 2 + dir)) * 16 + c) * 256 + d) * 64;
#pragma unroll
      for (int r = 0; r < 16; r += 2) {
        int n2 = (r & 3) + 8 * (r >> 2) + 4 * hi + rt * 32;
        float2 v;
        v.x = acc[rt][ct][r];
        v.y = acc[rt][ct][r + 1];
        *(float2*)(sp + n2) = v;
      }
    }
}

// ---------------- K_scan2: cross-chunk prefix (in-place on Sloc_T) ------
// grid (Bsz, 2, 4): d = bz*64 + tid>>2, h = tid&3 owns modes [h*8,h*8+8)
// dir0: chunks 0..15 ; dir1: chunks 15..0 (spatial chunk index both dirs)
__global__ __launch_bounds__(256) void k_scan2(
    const float* __restrict__ wtb, float* __restrict__ S) {
  const int b = blockIdx.x, dir = blockIdx.y;
  const int d = blockIdx.z * 64 + (threadIdx.x >> 2), h = threadIdx.x & 3;
  const int nbase = h * 8;
  float wTr[8], wTi[8], sr[8], si[8];
  const float* wt = wtb + (dir * 256 + d) * 64;
#pragma unroll
  for (int n = 0; n < 8; ++n) {
    wTr[n] = wt[2 * (nbase + n)];
    wTi[n] = wt[2 * (nbase + n) + 1];
    sr[n] = 0.f; si[n] = 0.f;
  }
  for (int cc = 0; cc < NCH; ++cc) {
    int c = dir ? (NCH - 1 - cc) : cc;
    float* p = S + ((((size_t)(b * 2 + dir)) * 16 + c) * 256 + d) * 64;
#pragma unroll
    for (int n = 0; n < 8; ++n) {
      int n2 = 2 * (nbase + n);
      float lr = p[n2], li = p[n2 + 1];
      p[n2] = sr[n]; p[n2 + 1] = si[n];
      float t0  = fmaf(wTr[n], sr[n], lr);
      float nsr = fmaf(-wTi[n], si[n], t0);
      float nsi = fmaf(wTr[n], si[n], li);
      nsi = fmaf(wTi[n], sr[n], nsi);
      sr[n] = nsr; si[n] = nsi;
    }
  }
}

// ---------------- K_mm2: Y = Toeplitz(K)@u + P@S + Dk*u, GELU -> ActT ---
// one wg per (d, dir); 512 thr = 8 waves; wave wv owns t rows [wv*32,+32)
// ActT layout: [ch = dir*256+d][m = b*4096 + c*256 + t] bf16
__global__ __launch_bounds__(512) void k_mm2(
    const _Float16* __restrict__ x16, const _Float16* __restrict__ KK,
    const _Float16* __restrict__ P, const float* __restrict__ Sstart,
    const float* __restrict__ Dskip, bf16* __restrict__ ActT) {
  const int d = blockIdx.x, dir = blockIdx.y;
  const int tid = threadIdx.x, lane = tid & 63, wv = tid >> 6;
  __shared__ __align__(16) _Float16 ub[64][272];   // [col][256 tau + 16 pad]
  __shared__ __align__(16) _Float16 sb[64][72];    // [col][64 n2 + 8 pad]
  __shared__ __align__(16) _Float16 kks[8][520];   // 8 shifted copies

  // stage shifted KK copies: kks[r][x] = KK[x+r] (zero-padded)
  {
    const _Float16* kg = KK + (dir * 256 + d) * 512;
#pragma unroll
    for (int rr = 0; rr < 8; ++rr)
      for (int xx = tid; xx < 520; xx += 512) {
        int s = xx + rr;
        kks[rr][xx] = (s < 512) ? kg[s] : (_Float16)0.f;
      }
  }
  const float Dk = Dskip[d];
  const int t = wv * 32 + (lane & 31);
  const int hi = lane >> 5;
  const int r_sh = (255 - t) & 7;
  const _Float16* pp = P + (size_t)(dir * 256 + d) * 256 * 64 + (size_t)t * 64;

  for (int cb = 0; cb < 4; ++cb) {
    __syncthreads();
    {  // stage u: 64 cols x 256 tau (32 halves = 4 x int4 per (col,part))
      int col = tid >> 3, part = tid & 7;
      int coll = cb * 64 + col;
      int b = coll >> 4, c = coll & 15;
      const _Float16* up = x16 + (size_t)d * 65536 + b * 4096 + c * 256 + part * 32;
      ((int4*)&ub[col][part * 32])[0] = ((const int4*)up)[0];
      ((int4*)&ub[col][part * 32])[1] = ((const int4*)up)[1];
      ((int4*)&ub[col][part * 32])[2] = ((const int4*)up)[2];
      ((int4*)&ub[col][part * 32])[3] = ((const int4*)up)[3];
    }
    {  // stage S: 64 cols x 64 n2 (fp32 -> fp16)
      int col = tid >> 3, part = tid & 7;
      int coll = cb * 64 + col;
      int b = coll >> 4, c = coll & 15;
      const float* sp = Sstart + ((((size_t)(b * 2 + dir)) * 16 + c) * 256 + d) * 64 + part * 8;
      float4 f0 = ((const float4*)sp)[0];
      float4 f1 = ((const float4*)sp)[1];
      half8 hv;
      hv[0]=(_Float16)f0.x; hv[1]=(_Float16)f0.y; hv[2]=(_Float16)f0.z; hv[3]=(_Float16)f0.w;
      hv[4]=(_Float16)f1.x; hv[5]=(_Float16)f1.y; hv[6]=(_Float16)f1.z; hv[7]=(_Float16)f1.w;
      *(half8*)&sb[col][part * 8] = hv;
    }
    __syncthreads();

    floatx16 acc0, acc1;
#pragma unroll
    for (int i = 0; i < 16; ++i) { acc0[i] = 0.f; acc1[i] = 0.f; }

    // conv: Y += Toeplitz @ u   (A[t][tau] = KK[255 - t + tau])
#pragma unroll
    for (int ks = 0; ks < 16; ++ks) {
      int i0 = 255 - t + ks * 16 + hi * 8;
      half8 af = *(const half8*)&kks[r_sh][i0 - r_sh];
      half8 b0 = *(const half8*)&ub[(lane & 31)][ks * 16 + hi * 8];
      half8 b1 = *(const half8*)&ub[32 + (lane & 31)][ks * 16 + hi * 8];
      acc0 = __builtin_amdgcn_mfma_f32_32x32x16_f16(af, b0, acc0, 0, 0, 0);
      acc1 = __builtin_amdgcn_mfma_f32_32x32x16_f16(af, b1, acc1, 0, 0, 0);
    }
    // boundary: Y += P @ S
#pragma unroll
    for (int ks = 0; ks < 4; ++ks) {
      half8 af = *(const half8*)(pp + ks * 16 + hi * 8);
      half8 b0 = *(const half8*)&sb[(lane & 31)][ks * 16 + hi * 8];
      half8 b1 = *(const half8*)&sb[32 + (lane & 31)][ks * 16 + hi * 8];
      acc0 = __builtin_amdgcn_mfma_f32_32x32x16_f16(af, b0, acc0, 0, 0, 0);
      acc1 = __builtin_amdgcn_mfma_f32_32x32x16_f16(af, b1, acc1, 0, 0, 0);
    }
    // epilogue: skip + gelu -> ActT (packed 2x bf16 per dword store)
#pragma unroll
    for (int ct = 0; ct < 2; ++ct) {
      int coll = cb * 64 + ct * 32 + (lane & 31);
      int b = coll >> 4, c = coll & 15;
      bf16* op = ActT + (size_t)(dir * 256 + d) * 65536 + b * 4096 + c * 256;
      int ucol = ct * 32 + (lane & 31);
#pragma unroll
      for (int r = 0; r < 16; r += 2) {
        int tt = (r & 3) + 8 * (r >> 2) + 4 * hi + wv * 32;
        float a0 = (ct ? acc1[r] : acc0[r]);
        float a1 = (ct ? acc1[r + 1] : acc0[r + 1]);
        float u0 = (float)ub[ucol][tt];
        float u1 = (float)ub[ucol][tt + 1];
        float g0 = gelu_tanh(fmaf(u0, Dk, a0));
        float g1 = gelu_tanh(fmaf(u1, Dk, a1));
        bf16 h0 = __float2bfloat16(g0);
        bf16 h1 = __float2bfloat16(g1);
        unsigned pk = (unsigned)*(unsigned short*)&h0 |
                      ((unsigned)*(unsigned short*)&h1 << 16);
        *(unsigned*)(op + tt) = pk;
      }
    }
  }
}

// ---------------- K_tr2: ActT[ch][m] -> Act[m][ch] (bf16) ---------------
__global__ __launch_bounds__(256) void k_tr2(
    const bf16* __restrict__ AT, bf16* __restrict__ A) {
  __shared__ __align__(16) short tl[64][72];
  const int m0 = blockIdx.x * 64, ch0 = blockIdx.y * 64;
  const int tid = threadIdx.x;
  {
    int chi = tid >> 2, mq = (tid & 3) * 16;
    const short* src = (const short*)AT + (size_t)(ch0 + chi) * 65536 + m0 + mq;
    *(int4*)&tl[chi][mq] = ((const int4*)src)[0];
    *(int4*)&tl[chi][mq + 8] = ((const int4*)src)[1];
  }
  __syncthreads();
  {
    int mi = tid >> 2, chq = (tid & 3) * 16;
    short8 s0, s1;
#pragma unroll
    for (int i = 0; i < 8; ++i) {
      s0[i] = tl[chq + i][mi];
      s1[i] = tl[chq + 8 + i][mi];
    }
    short* dst = (short*)A + (size_t)(m0 + mi) * 512 + ch0 + chq;
    ((short8*)dst)[0] = s0;
    ((short8*)dst)[1] = s1;
  }
}

// ---------------- K4: GEMM (M,K=512)x(1024,K) + bias + GLU -> z ---------
// v5: fragment-major LDS + double buffer, 1 barrier/K-step.
// Round-8: LDK=40 row-major LDS -> ~8-way bank conflict (1.678e7 cyc).
// Round-9: no LDS -> L2-latency-bound (all counters ~11%).
// Fix: store each 16-row x 32-k sub-tile as a 1KB block in LANE ORDER:
// (kchunk*16 + row_in_block) == lane, so fragment ds_read_b128 is a
// CONTIGUOUS 1KB wave read (zero conflicts) and staging ds_write is
// slot = linear tid -> contiguous too. Staging source re-derived:
// thread t loads global row (t>>6)*16+(t&15), kchunk (t>>4)&3.
__global__ __launch_bounds__(256, 4) void k_gemm(
    const bf16* __restrict__ Act, const bf16* __restrict__ W,
    const float* __restrict__ bias, float* __restrict__ z) {
  // per buffer (shorts): A 4096 (8x1KB blocks), Ba 2048 @4096, Bg 2048 @6144
  __shared__ __align__(16) short lds[2][8192];
  const int id = blockIdx.x;
  const int x = id & 7, nj = (id >> 3) & 7, g = id >> 6;
  const int bi = g * 8 + x;
  const int tid = threadIdx.x, lane = tid & 63, wv = tid >> 6;
  const int wm = (wv & 1) * 64, wn = (wv >> 1) * 32;
  const int M0 = bi * 128, N0 = nj * 64;
  floatx4 acc_a[4][2], acc_g[4][2];
#pragma unroll
  for (int i = 0; i < 4; ++i)
#pragma unroll
    for (int j = 0; j < 2; ++j) {
      acc_a[i][j] = (floatx4){0.f, 0.f, 0.f, 0.f};
      acc_g[i][j] = (floatx4){0.f, 0.f, 0.f, 0.f};
    }
  // staging source: row block q=tid>>6, row-in-block tid&15, kchunk (tid>>4)&3
  const int q = tid >> 6, rl = tid & 15, kch = (tid >> 4) & 3;
  const bf16* gA0 = Act + (size_t)(M0 + q * 16 + rl) * 512 + kch * 8;
  const bf16* gA1 = gA0 + (size_t)64 * 512;
  const bf16* gBa = W + (size_t)(N0 + q * 16 + rl) * 512 + kch * 8;
  const bf16* gBg = gBa + (size_t)512 * 512;

  // prologue: stage k-tile 0 into buf 0
  {
    int4 a0 = *(const int4*)gA0;
    int4 a1 = *(const int4*)gA1;
    int4 b0 = *(const int4*)gBa;
    int4 b1 = *(const int4*)gBg;
    short* dst = &lds[0][0];
    *(int4*)(dst + tid * 8)        = a0;
    *(int4*)(dst + 2048 + tid * 8) = a1;
    *(int4*)(dst + 4096 + tid * 8) = b0;
    *(int4*)(dst + 6144 + tid * 8) = b1;
  }
  int cur = 0;
  const int ablk = (wv & 1) * 4;        // A block base for this wave
  const int bblk = (wv >> 1) * 2;       // B block base

  for (int kb = 0; kb < 512; kb += 32) {
    __syncthreads();   // staged tile in buf[cur] visible; buf[cur^1] free
    const short* bufp = &lds[cur][0];
    short8 af[4], bfa[2], bfg[2];
#pragma unroll
    for (int i = 0; i < 4; ++i)
      af[i] = *(const short8*)(bufp + (ablk + i) * 512 + lane * 8);
#pragma unroll
    for (int j = 0; j < 2; ++j) {
      bfa[j] = *(const short8*)(bufp + 4096 + (bblk + j) * 512 + lane * 8);
      bfg[j] = *(const short8*)(bufp + 6144 + (bblk + j) * 512 + lane * 8);
    }
    // issue next-tile global loads; they land during the MFMA cluster
    int4 ga0, ga1, gb, gg;
    const bool more = (kb + 32) < 512;
    if (more) {
      ga0 = *(const int4*)(gA0 + kb + 32);
      ga1 = *(const int4*)(gA1 + kb + 32);
      gb  = *(const int4*)(gBa + kb + 32);
      gg  = *(const int4*)(gBg + kb + 32);
    }
#pragma unroll
    for (int i = 0; i < 4; ++i)
#pragma unroll
      for (int j = 0; j < 2; ++j) {
        acc_a[i][j] = __builtin_amdgcn_mfma_f32_16x16x32_bf16(af[i], bfa[j], acc_a[i][j], 0, 0, 0);
        acc_g[i][j] = __builtin_amdgcn_mfma_f32_16x16x32_bf16(af[i], bfg[j], acc_g[i][j], 0, 0, 0);
      }
    if (more) {
      short* dst = &lds[cur ^ 1][0];
      *(int4*)(dst + tid * 8)        = ga0;
      *(int4*)(dst + 2048 + tid * 8) = ga1;
      *(int4*)(dst + 4096 + tid * 8) = gb;
      *(int4*)(dst + 6144 + tid * 8) = gg;
    }
    cur ^= 1;
  }
  // epilogue: bias + GLU, write z[m][o] fp32, o in [N0, N0+64)
  const int col = lane & 15, rquad = (lane >> 4) * 4;
#pragma unroll
  for (int j = 0; j < 2; ++j) {
    int o = N0 + wn + 16 * j + col;
    float ba = bias[o];
    float bg = bias[512 + o];
#pragma unroll
    for (int i = 0; i < 4; ++i) {
      int mbase = M0 + wm + 16 * i + rquad;
#pragma unroll
      for (int rg = 0; rg < 4; ++rg) {
        float a = acc_a[i][j][rg] + ba;
        float g = acc_g[i][j][rg] + bg;
        float zv = a * __frcp_rn(1.f + __expf(-g));
        z[(size_t)(mbase + rg) * 512 + o] = zv;
      }
    }
  }
}

// ---------------- K5: LayerNorm over 512 (in-place on d_out) ------------
__global__ __launch_bounds__(256) void k_ln(
    float* __restrict__ z, const float* __restrict__ gamma,
    const float* __restrict__ beta) {
  const int m = blockIdx.x * 4 + (threadIdx.x >> 6);
  const int lane = threadIdx.x & 63;
  float* zp = z + (size_t)m * 512;
  float v[8], s = 0.f, sq = 0.f;
#pragma unroll
  for (int j = 0; j < 8; ++j) {
    v[j] = zp[j * 64 + lane];
    s += v[j];
    sq = fmaf(v[j], v[j], sq);
  }
#pragma unroll
  for (int off = 32; off > 0; off >>= 1) {
    s += __shfl_xor(s, off);
    sq += __shfl_xor(sq, off);
  }
  float mean = s * (1.f / 512.f);
  float var = fmaf(-mean, mean, sq * (1.f / 512.f));
  float inv = rsqrtf(var + 1e-5f);
#pragma unroll
  for (int j = 0; j < 8; ++j) {
    int cidx = j * 64 + lane;
    float g = gamma[cidx], be = beta[cidx];
    zp[cidx] = fmaf((v[j] - mean) * inv, g, be);
  }
}

extern "C" void kernel_launch(void* const* d_in, const int* in_sizes, int n_in,
                              void* d_out, int out_size, void* d_ws, size_t ws_size,
                              hipStream_t stream) {
  const float* x      = (const float*)d_in[0];
  const float* ldt_fw = (const float*)d_in[1];
  const float* lar_fw = (const float*)d_in[2];
  const float* ai_fw  = (const float*)d_in[3];
  const float* C_fw   = (const float*)d_in[4];
  const float* ldt_bw = (const float*)d_in[5];
  const float* lar_bw = (const float*)d_in[6];
  const float* ai_bw  = (const float*)d_in[7];
  const float* C_bw   = (const float*)d_in[8];
  const float* Dskip  = (const float*)d_in[9];
  const float* W      = (const float*)d_in[10];
  const float* bias   = (const float*)d_in[11];
  const float* gamma  = (const float*)d_in[12];
  const float* beta   = (const float*)d_in[13];
  float* out = (float*)d_out;

  // workspace map (bytes):
  //  [0)          ActT   512*65536*2  = 67,108,864
  //  [67108864)   SlocT  16*2*16*256*64*4 = 33,554,432
  //  [100663296)  x16    256*65536*2  = 33,554,432
  //  [134217728)  Vm     2*256*64*256*2 = 16,777,216
  //  [150994944)  P      2*256*256*64*2 = 16,777,216
  //  [167772160)  KK     2*256*512*2  = 524,288
  //  [168296448)  wtb    2*256*64*4   = 131,072
  //  [168427520)  Wb     1,048,576     -> total ~169.5 MB
  //  Act (final [m][ch], 67,108,864 B) aliases [SlocT + x16]; both dead by k_tr2.
  char* wsb = (char*)d_ws;
  bf16*     ActT  = (bf16*)wsb;
  float*    SlocT = (float*)(wsb + 67108864u);
  _Float16* x16   = (_Float16*)(wsb + 100663296u);
  _Float16* Vm    = (_Float16*)(wsb + 134217728u);
  _Float16* P     = (_Float16*)(wsb + 150994944u);
  _Float16* KK    = (_Float16*)(wsb + 167772160u);
  float*    wtb   = (float*)(wsb + 168296448u);
  bf16*     Wb    = (bf16*)(wsb + 168427520u);
  bf16*     Act   = (bf16*)(wsb + 67108864u);   // alias over SlocT+x16

  k_prep<<<dim3(256, 2), dim3(64), 0, stream>>>(
      ldt_fw, lar_fw, ai_fw, C_fw, ldt_bw, lar_bw, ai_bw, C_bw, Vm, P, KK, wtb);
  k_wconv<<<dim3(2048), dim3(256), 0, stream>>>(W, Wb, 1024 * 512);
  k_tr<<<dim3(Mtot / 64, 4), dim3(256), 0, stream>>>(x, x16);
  k_mm1<<<dim3(256, 2), dim3(256), 0, stream>>>(x16, Vm, SlocT);
  k_scan2<<<dim3(Bsz, 2, 4), dim3(256), 0, stream>>>(wtb, SlocT);
  k_mm2<<<dim3(256, 2), dim3(512), 0, stream>>>(x16, KK, P, SlocT, Dskip, ActT);
  k_tr2<<<dim3(Mtot / 64, 8), dim3(256), 0, stream>>>(ActT, Act);
  k_gemm<<<dim3(4096), dim3(256), 0, stream>>>(Act, Wb, bias, out);
  k_ln<<<dim3(Mtot / 4), dim3(256), 0, stream>>>(out, gamma, beta);
}

// Round 11
// 554.385 us; speedup vs baseline: 1.2071x; 1.0062x over previous
//
#include <hip/hip_runtime.h>
#include <hip/hip_bf16.h>
#include <cstdint>
#include <cstddef>

typedef __hip_bfloat16 bf16;
typedef __attribute__((ext_vector_type(8))) short short8;
typedef __attribute__((ext_vector_type(4))) float floatx4;
typedef __attribute__((ext_vector_type(16))) float floatx16;
typedef __attribute__((ext_vector_type(8))) _Float16 half8;

typedef __attribute__((address_space(3))) uint32_t lds_u32;
typedef __attribute__((address_space(1))) const uint32_t glb_u32;

#define Bsz 16
#define Lseq 4096
#define Hd 256
#define NM 32          // complex modes per channel
#define NCH 16         // chunks
#define TCH 256        // chunk length (NCH*TCH == Lseq)
#define Mtot (Bsz*Lseq)

__device__ __forceinline__ float gelu_tanh(float y) {
  float y2 = y * y;
  float q = fmaf(0.044715f, y2, 1.0f);
  float a = 1.5957691216057308f * y * q;
  float e = __expf(-a);
  return y * __frcp_rn(1.0f + e);
}

// ---------------- K_prep: per-(dir,d) tables for the matmul formulation ---
// KK[dir][d][512]  fp16: dir0: KK[i]=K[255-i] (i<=255) else 0  (A[t][tau]=KK[255-t+tau])
//                        dir1: KK[i]=K[i-255] (i>=255) else 0
// Vm[dir][d][n2][256] fp16: dir0: Vm[2n][tau]=Re(w^{255-tau}) ; dir1: Re(w^{tau})
// P [dir][d][256][64] fp16: dir0: P[t][2n]=Re(C w^{t+1}), [2n+1]=-Im(C w^{t+1})
//                           dir1: exponent 256-t
// wtb[dir][d][64] fp32: [2n]=Re(w^256), [2n+1]=Im(w^256)
__global__ __launch_bounds__(64) void k_prep(
    const float* __restrict__ ldt_fw, const float* __restrict__ lar_fw,
    const float* __restrict__ ai_fw,  const float* __restrict__ C_fw,
    const float* __restrict__ ldt_bw, const float* __restrict__ lar_bw,
    const float* __restrict__ ai_bw,  const float* __restrict__ C_bw,
    _Float16* __restrict__ Vm, _Float16* __restrict__ P,
    _Float16* __restrict__ KK, float* __restrict__ wtb) {
  const int d = blockIdx.x, dir = blockIdx.y;
  const int lane = threadIdx.x;
  const int n = lane & 31;
  const bool active = lane < 32;
  const float* ldt = dir ? ldt_bw : ldt_fw;
  const float* lar = dir ? lar_bw : lar_fw;
  const float* ai  = dir ? ai_bw  : ai_fw;
  const float* C   = dir ? C_bw   : C_fw;

  float dt = expf(ldt[d]);
  float Ar = -expf(lar[d * NM + n]);
  float Ai = ai[d * NM + n];
  float c0 = C[(d * NM + n) * 2 + 0];
  float c1 = C[(d * NM + n) * 2 + 1];

  float er = expf(Ar * dt);
  float sn, cs;
  sincosf(Ai * dt, &sn, &cs);
  float wr = er * cs, wi = er * sn;
  // Ceff = 2*Cc*(w-1)/(A+1e-8)
  float nr = wr - 1.f, ni = wi;
  float tr_ = c0 * nr - c1 * ni;
  float ti  = c0 * ni + c1 * nr;
  float dr = Ar + 1e-8f, di = Ai;
  float inv = 1.f / (dr * dr + di * di);
  float Cr = 2.f * (tr_ * dr + ti * di) * inv;
  float Ci = 2.f * (ti * dr - tr_ * di) * inv;
  // wT = w^256 (direct exp for accuracy)
  float erT = expf(256.f * Ar * dt);
  float snT, csT;
  sincosf(256.f * Ai * dt, &snT, &csT);
  if (active) {
    wtb[(dir * 256 + d) * 64 + 2 * n]     = erT * csT;
    wtb[(dir * 256 + d) * 64 + 2 * n + 1] = erT * snT;
  }
  // zero KK
  _Float16* kk = KK + (dir * 256 + d) * 512;
  for (int i = lane; i < 512; i += 64) kk[i] = (_Float16)0.f;
  __syncthreads();

  _Float16* vm = Vm + (size_t)(dir * 256 + d) * 64 * 256;
  _Float16* pp = P  + (size_t)(dir * 256 + d) * 256 * 64;
  float pr = 1.f, pi = 0.f;  // w^j
  for (int j = 0; j <= 256; ++j) {
    float kc = active ? (Cr * pr - Ci * pi) : 0.f;
#pragma unroll
    for (int off = 32; off > 0; off >>= 1) kc += __shfl_xor(kc, off);
    if (lane == 0 && j <= 255) {
      int i = dir ? (255 + j) : (255 - j);
      kk[i] = (_Float16)kc;
    }
    if (active) {
      if (j <= 255) {
        int tv = dir ? j : (255 - j);
        vm[(2 * n) * 256 + tv]     = (_Float16)pr;
        vm[(2 * n + 1) * 256 + tv] = (_Float16)pi;
      }
      if (j >= 1) {
        int t = dir ? (256 - j) : (j - 1);
        float cwr = Cr * pr - Ci * pi;
        float cwi = Cr * pi + Ci * pr;
        pp[t * 64 + 2 * n]     = (_Float16)cwr;
        pp[t * 64 + 2 * n + 1] = (_Float16)(-cwi);
      }
    }
    float npr = pr * wr - pi * wi;
    float npi = pr * wi + pi * wr;
    pr = npr; pi = npi;
  }
}

// ---------------- K0b: conv_w fp32 -> bf16 ----------------
__global__ __launch_bounds__(256) void k_wconv(
    const float* __restrict__ W, bf16* __restrict__ Wb, int n) {
  int i = blockIdx.x * 256 + threadIdx.x;
  if (i < n) Wb[i] = __float2bfloat16(W[i]);
}

// ---------------- K_tr: x[m=b*L+l][d] fp32 -> x16[d][m] fp16 ------------
__global__ __launch_bounds__(256) void k_tr(
    const float* __restrict__ x, _Float16* __restrict__ x16) {
  __shared__ __align__(16) _Float16 t16[64][72];
  const int m0 = blockIdx.x * 64, d0 = blockIdx.y * 64;
  const int tid = threadIdx.x;
  {
    int li = tid >> 2, dq = (tid & 3) * 16;
    const float* src = x + (size_t)(m0 + li) * 256 + d0 + dq;
    float4 v0 = ((const float4*)src)[0];
    float4 v1 = ((const float4*)src)[1];
    float4 v2 = ((const float4*)src)[2];
    float4 v3 = ((const float4*)src)[3];
    half8 h0, h1;
    h0[0]=(_Float16)v0.x; h0[1]=(_Float16)v0.y; h0[2]=(_Float16)v0.z; h0[3]=(_Float16)v0.w;
    h0[4]=(_Float16)v1.x; h0[5]=(_Float16)v1.y; h0[6]=(_Float16)v1.z; h0[7]=(_Float16)v1.w;
    h1[0]=(_Float16)v2.x; h1[1]=(_Float16)v2.y; h1[2]=(_Float16)v2.z; h1[3]=(_Float16)v2.w;
    h1[4]=(_Float16)v3.x; h1[5]=(_Float16)v3.y; h1[6]=(_Float16)v3.z; h1[7]=(_Float16)v3.w;
    *(half8*)&t16[li][dq] = h0;
    *(half8*)&t16[li][dq + 8] = h1;
  }
  __syncthreads();
  {
    int dj = tid >> 2, lq = (tid & 3) * 16;
    half8 o0, o1;
#pragma unroll
    for (int i = 0; i < 8; ++i) {
      o0[i] = t16[lq + i][dj];
      o1[i] = t16[lq + 8 + i][dj];
    }
    _Float16* dst = x16 + (size_t)(d0 + dj) * 65536 + m0 + lq;
    ((half8*)dst)[0] = o0;
    ((half8*)dst)[1] = o1;
  }
}

// ---------------- K_mm1: chunk-local states L = Vm @ u ------------------
// one wg per (d, dir); 256 thr = 4 waves, wave wv owns 64 cols (col=b*16+c)
// Sloc_T layout: [b][dir][c][d][n2(64)] fp32
__global__ __launch_bounds__(256) void k_mm1(
    const _Float16* __restrict__ x16, const _Float16* __restrict__ Vm,
    float* __restrict__ Sloc) {
  const int d = blockIdx.x, dir = blockIdx.y;
  const int tid = threadIdx.x, lane = tid & 63, wv = tid >> 6;
  __shared__ __align__(16) _Float16 ub[256][24];  // 16 tau + 8 pad
  floatx16 acc[2][2];
#pragma unroll
  for (int a = 0; a < 2; ++a)
#pragma unroll
    for (int b = 0; b < 2; ++b)
#pragma unroll
      for (int i = 0; i < 16; ++i) acc[a][b][i] = 0.f;

  const _Float16* vmp = Vm + (size_t)(dir * 256 + d) * 64 * 256;
  const int arow = lane & 31, ak = (lane >> 5) * 8;
  const int colb = wv * 64;

  for (int ks = 0; ks < 16; ++ks) {
    const int tau0 = ks * 16;
    __syncthreads();
    {
      int col = tid;
      int b = col >> 4, c = col & 15;
      const _Float16* up = x16 + (size_t)d * 65536 + b * 4096 + c * 256 + tau0;
      ((int4*)&ub[col][0])[0] = ((const int4*)up)[0];
      ((int4*)&ub[col][0])[1] = ((const int4*)up)[1];
    }
    __syncthreads();
    half8 a0 = *(const half8*)(vmp + (size_t)(0 * 32 + arow) * 256 + tau0 + ak);
    half8 a1 = *(const half8*)(vmp + (size_t)(1 * 32 + arow) * 256 + tau0 + ak);
    half8 b0 = *(const half8*)&ub[colb + arow][ak];
    half8 b1 = *(const half8*)&ub[colb + 32 + arow][ak];
    acc[0][0] = __builtin_amdgcn_mfma_f32_32x32x16_f16(a0, b0, acc[0][0], 0, 0, 0);
    acc[0][1] = __builtin_amdgcn_mfma_f32_32x32x16_f16(a0, b1, acc[0][1], 0, 0, 0);
    acc[1][0] = __builtin_amdgcn_mfma_f32_32x32x16_f16(a1, b0, acc[1][0], 0, 0, 0);
    acc[1][1] = __builtin_amdgcn_mfma_f32_32x32x16_f16(a1, b1, acc[1][1], 0, 0, 0);
  }
  const int hi = lane >> 5;
#pragma unroll
  for (int rt = 0; rt < 2; ++rt)
#pragma unroll
    for (int ct = 0; ct < 2; ++ct) {
      int coll = colb + ct * 32 + (lane & 31);
      int b = coll >> 4, c = coll & 15;
      float* sp = Sloc + ((((size_t)(b * 2 + dir)) * 16 + c) * 256 + d) * 64;
#pragma unroll
      for (int r = 0; r < 16; r += 2) {
        int n2 = (r & 3) + 8 * (r >> 2) + 4 * hi + rt * 32;
        float2 v;
        v.x = acc[rt][ct][r];
        v.y = acc[rt][ct][r + 1];
        *(float2*)(sp + n2) = v;
      }
    }
}

// ---------------- K_scan2: cross-chunk prefix (in-place on Sloc_T) ------
// grid (Bsz, 2, 4): d = bz*64 + tid>>2, h = tid&3 owns modes [h*8,h*8+8)
// dir0: chunks 0..15 ; dir1: chunks 15..0 (spatial chunk index both dirs)
__global__ __launch_bounds__(256) void k_scan2(
    const float* __restrict__ wtb, float* __restrict__ S) {
  const int b = blockIdx.x, dir = blockIdx.y;
  const int d = blockIdx.z * 64 + (threadIdx.x >> 2), h = threadIdx.x & 3;
  const int nbase = h * 8;
  float wTr[8], wTi[8], sr[8], si[8];
  const float* wt = wtb + (dir * 256 + d) * 64;
#pragma unroll
  for (int n = 0; n < 8; ++n) {
    wTr[n] = wt[2 * (nbase + n)];
    wTi[n] = wt[2 * (nbase + n) + 1];
    sr[n] = 0.f; si[n] = 0.f;
  }
  for (int cc = 0; cc < NCH; ++cc) {
    int c = dir ? (NCH - 1 - cc) : cc;
    float* p = S + ((((size_t)(b * 2 + dir)) * 16 + c) * 256 + d) * 64;
#pragma unroll
    for (int n = 0; n < 8; ++n) {
      int n2 = 2 * (nbase + n);
      float lr = p[n2], li = p[n2 + 1];
      p[n2] = sr[n]; p[n2 + 1] = si[n];
      float t0  = fmaf(wTr[n], sr[n], lr);
      float nsr = fmaf(-wTi[n], si[n], t0);
      float nsi = fmaf(wTr[n], si[n], li);
      nsi = fmaf(wTi[n], sr[n], nsi);
      sr[n] = nsr; si[n] = nsi;
    }
  }
}

// ---------------- K_mm2: Y = Toeplitz(K)@u + P@S + Dk*u, GELU -> ActT ---
// one wg per (d, dir); 512 thr = 8 waves; wave wv owns t rows [wv*32,+32)
// ub stride 264 (528B = 132 dwords, gcd(132,32)=4): fragment col-reads hit
// 8 distinct bank-groups -> 4-way conflict (the floor for b128 col reads);
// round-10's 272 (136 dw, gcd 8) was 8-way.
// ActT layout: [ch = dir*256+d][m = b*4096 + c*256 + t] bf16
__global__ __launch_bounds__(512) void k_mm2(
    const _Float16* __restrict__ x16, const _Float16* __restrict__ KK,
    const _Float16* __restrict__ P, const float* __restrict__ Sstart,
    const float* __restrict__ Dskip, bf16* __restrict__ ActT) {
  const int d = blockIdx.x, dir = blockIdx.y;
  const int tid = threadIdx.x, lane = tid & 63, wv = tid >> 6;
  __shared__ __align__(16) _Float16 ub[64][264];   // [col][256 tau + 8 pad]
  __shared__ __align__(16) _Float16 sb[64][72];    // [col][64 n2 + 8 pad]
  __shared__ __align__(16) _Float16 kks[8][520];   // 8 shifted copies

  // stage shifted KK copies: kks[r][x] = KK[x+r] (zero-padded)
  {
    const _Float16* kg = KK + (dir * 256 + d) * 512;
#pragma unroll
    for (int rr = 0; rr < 8; ++rr)
      for (int xx = tid; xx < 520; xx += 512) {
        int s = xx + rr;
        kks[rr][xx] = (s < 512) ? kg[s] : (_Float16)0.f;
      }
  }
  const float Dk = Dskip[d];
  const int t = wv * 32 + (lane & 31);
  const int hi = lane >> 5;
  const int r_sh = (255 - t) & 7;
  const _Float16* pp = P + (size_t)(dir * 256 + d) * 256 * 64 + (size_t)t * 64;

  for (int cb = 0; cb < 4; ++cb) {
    __syncthreads();
    {  // stage u: 64 cols x 256 tau (32 halves = 4 x int4 per (col,part))
      int col = tid >> 3, part = tid & 7;
      int coll = cb * 64 + col;
      int b = coll >> 4, c = coll & 15;
      const _Float16* up = x16 + (size_t)d * 65536 + b * 4096 + c * 256 + part * 32;
      ((int4*)&ub[col][part * 32])[0] = ((const int4*)up)[0];
      ((int4*)&ub[col][part * 32])[1] = ((const int4*)up)[1];
      ((int4*)&ub[col][part * 32])[2] = ((const int4*)up)[2];
      ((int4*)&ub[col][part * 32])[3] = ((const int4*)up)[3];
    }
    {  // stage S: 64 cols x 64 n2 (fp32 -> fp16)
      int col = tid >> 3, part = tid & 7;
      int coll = cb * 64 + col;
      int b = coll >> 4, c = coll & 15;
      const float* sp = Sstart + ((((size_t)(b * 2 + dir)) * 16 + c) * 256 + d) * 64 + part * 8;
      float4 f0 = ((const float4*)sp)[0];
      float4 f1 = ((const float4*)sp)[1];
      half8 hv;
      hv[0]=(_Float16)f0.x; hv[1]=(_Float16)f0.y; hv[2]=(_Float16)f0.z; hv[3]=(_Float16)f0.w;
      hv[4]=(_Float16)f1.x; hv[5]=(_Float16)f1.y; hv[6]=(_Float16)f1.z; hv[7]=(_Float16)f1.w;
      *(half8*)&sb[col][part * 8] = hv;
    }
    __syncthreads();

    floatx16 acc0, acc1;
#pragma unroll
    for (int i = 0; i < 16; ++i) { acc0[i] = 0.f; acc1[i] = 0.f; }

    // conv: Y += Toeplitz @ u   (A[t][tau] = KK[255 - t + tau])
#pragma unroll
    for (int ks = 0; ks < 16; ++ks) {
      int i0 = 255 - t + ks * 16 + hi * 8;
      half8 af = *(const half8*)&kks[r_sh][i0 - r_sh];
      half8 b0 = *(const half8*)&ub[(lane & 31)][ks * 16 + hi * 8];
      half8 b1 = *(const half8*)&ub[32 + (lane & 31)][ks * 16 + hi * 8];
      acc0 = __builtin_amdgcn_mfma_f32_32x32x16_f16(af, b0, acc0, 0, 0, 0);
      acc1 = __builtin_amdgcn_mfma_f32_32x32x16_f16(af, b1, acc1, 0, 0, 0);
    }
    // boundary: Y += P @ S
#pragma unroll
    for (int ks = 0; ks < 4; ++ks) {
      half8 af = *(const half8*)(pp + ks * 16 + hi * 8);
      half8 b0 = *(const half8*)&sb[(lane & 31)][ks * 16 + hi * 8];
      half8 b1 = *(const half8*)&sb[32 + (lane & 31)][ks * 16 + hi * 8];
      acc0 = __builtin_amdgcn_mfma_f32_32x32x16_f16(af, b0, acc0, 0, 0, 0);
      acc1 = __builtin_amdgcn_mfma_f32_32x32x16_f16(af, b1, acc1, 0, 0, 0);
    }
    // epilogue: skip + gelu -> ActT (packed 2x bf16 per dword store)
#pragma unroll
    for (int ct = 0; ct < 2; ++ct) {
      int coll = cb * 64 + ct * 32 + (lane & 31);
      int b = coll >> 4, c = coll & 15;
      bf16* op = ActT + (size_t)(dir * 256 + d) * 65536 + b * 4096 + c * 256;
      int ucol = ct * 32 + (lane & 31);
#pragma unroll
      for (int r = 0; r < 16; r += 2) {
        int tt = (r & 3) + 8 * (r >> 2) + 4 * hi + wv * 32;
        float a0 = (ct ? acc1[r] : acc0[r]);
        float a1 = (ct ? acc1[r + 1] : acc0[r + 1]);
        float u0 = (float)ub[ucol][tt];
        float u1 = (float)ub[ucol][tt + 1];
        float g0 = gelu_tanh(fmaf(u0, Dk, a0));
        float g1 = gelu_tanh(fmaf(u1, Dk, a1));
        bf16 h0 = __float2bfloat16(g0);
        bf16 h1 = __float2bfloat16(g1);
        unsigned pk = (unsigned)*(unsigned short*)&h0 |
                      ((unsigned)*(unsigned short*)&h1 << 16);
        *(unsigned*)(op + tt) = pk;
      }
    }
  }
}

// ---------------- K_tr2: ActT[ch][m] -> Act[m][ch] (bf16) ---------------
__global__ __launch_bounds__(256) void k_tr2(
    const bf16* __restrict__ AT, bf16* __restrict__ A) {
  __shared__ __align__(16) short tl[64][72];
  const int m0 = blockIdx.x * 64, ch0 = blockIdx.y * 64;
  const int tid = threadIdx.x;
  {
    int chi = tid >> 2, mq = (tid & 3) * 16;
    const short* src = (const short*)AT + (size_t)(ch0 + chi) * 65536 + m0 + mq;
    *(int4*)&tl[chi][mq] = ((const int4*)src)[0];
    *(int4*)&tl[chi][mq + 8] = ((const int4*)src)[1];
  }
  __syncthreads();
  {
    int mi = tid >> 2, chq = (tid & 3) * 16;
    short8 s0, s1;
#pragma unroll
    for (int i = 0; i < 8; ++i) {
      s0[i] = tl[chq + i][mi];
      s1[i] = tl[chq + 8 + i][mi];
    }
    short* dst = (short*)A + (size_t)(m0 + mi) * 512 + ch0 + chq;
    ((short8*)dst)[0] = s0;
    ((short8*)dst)[1] = s1;
  }
}

// ---------------- K4: GEMM (M,K=512)x(1024,K) + bias + GLU -> z ---------
// v6: fragment-major LDS + global_load_lds (T3 2-phase recipe).
// Round-10 (v5) diagnosis: conflicts 0 but reg-staged loads consumed
// same-iteration -> vmcnt wait before ds_write exposed L2 latency every
// K-step (MfmaUtil 20, VALU 19, all idle).
// Fix: fragment-major layout is linear in tid (dst + tid*16B = wave base
// + lane*16) == EXACTLY global_load_lds's dest constraint. STAGE(t+1) at
// top of iter t; one __syncthreads at bottom (its vmcnt(0) drain IS the
// recipe's "vmcnt(0);barrier" — loads get ds_read+MFMA time to fly).
// Stage writes buf[cur^1] while reading buf[cur]: race-free.
__global__ __launch_bounds__(256, 4) void k_gemm(
    const bf16* __restrict__ Act, const bf16* __restrict__ W,
    const float* __restrict__ bias, float* __restrict__ z) {
  // per buffer (shorts): A 4096 (8x1KB blocks), Ba 2048 @4096, Bg 2048 @6144
  __shared__ __align__(16) short lds[2][8192];
  const int id = blockIdx.x;
  const int x = id & 7, nj = (id >> 3) & 7, g = id >> 6;
  const int bi = g * 8 + x;
  const int tid = threadIdx.x, lane = tid & 63, wv = tid >> 6;
  const int wm = (wv & 1) * 64, wn = (wv >> 1) * 32;
  const int M0 = bi * 128, N0 = nj * 64;
  floatx4 acc_a[4][2], acc_g[4][2];
#pragma unroll
  for (int i = 0; i < 4; ++i)
#pragma unroll
    for (int j = 0; j < 2; ++j) {
      acc_a[i][j] = (floatx4){0.f, 0.f, 0.f, 0.f};
      acc_g[i][j] = (floatx4){0.f, 0.f, 0.f, 0.f};
    }
  // staging source: row block q=tid>>6, row-in-block tid&15, kchunk (tid>>4)&3
  const int q = tid >> 6, rl = tid & 15, kch = (tid >> 4) & 3;
  const bf16* gA0 = Act + (size_t)(M0 + q * 16 + rl) * 512 + kch * 8;
  const bf16* gA1 = gA0 + (size_t)64 * 512;
  const bf16* gBa = W + (size_t)(N0 + q * 16 + rl) * 512 + kch * 8;
  const bf16* gBg = gBa + (size_t)512 * 512;

  // STAGE: 4 direct-to-LDS loads; HW writes wave_base + lane*16
  auto stage = [&](int buf, int kb) {
    char* base = (char*)&lds[buf][0] + wv * 1024;
    __builtin_amdgcn_global_load_lds((glb_u32*)(const void*)(gA0 + kb), (lds_u32*)(base),         16, 0, 0);
    __builtin_amdgcn_global_load_lds((glb_u32*)(const void*)(gA1 + kb), (lds_u32*)(base + 4096),  16, 0, 0);
    __builtin_amdgcn_global_load_lds((glb_u32*)(const void*)(gBa + kb), (lds_u32*)(base + 8192),  16, 0, 0);
    __builtin_amdgcn_global_load_lds((glb_u32*)(const void*)(gBg + kb), (lds_u32*)(base + 12288), 16, 0, 0);
  };

  stage(0, 0);
  __syncthreads();           // vmcnt(0) drain: tile 0 staged, all waves synced

  const int ablk = (wv & 1) * 4;        // A block base for this wave
  const int bblk = (wv >> 1) * 2;       // B block base

  for (int t = 0; t < 16; ++t) {
    const int cur = t & 1;
    if (t < 15) stage(cur ^ 1, (t + 1) * 32);   // issue next-tile DMA first
    const short* bufp = &lds[cur][0];
    short8 af[4], bfa[2], bfg[2];
#pragma unroll
    for (int i = 0; i < 4; ++i)
      af[i] = *(const short8*)(bufp + (ablk + i) * 512 + lane * 8);
#pragma unroll
    for (int j = 0; j < 2; ++j) {
      bfa[j] = *(const short8*)(bufp + 4096 + (bblk + j) * 512 + lane * 8);
      bfg[j] = *(const short8*)(bufp + 6144 + (bblk + j) * 512 + lane * 8);
    }
#pragma unroll
    for (int i = 0; i < 4; ++i)
#pragma unroll
      for (int j = 0; j < 2; ++j) {
        acc_a[i][j] = __builtin_amdgcn_mfma_f32_16x16x32_bf16(af[i], bfa[j], acc_a[i][j], 0, 0, 0);
        acc_g[i][j] = __builtin_amdgcn_mfma_f32_16x16x32_bf16(af[i], bfg[j], acc_g[i][j], 0, 0, 0);
      }
    __syncthreads();         // drains stage DMA + all reads of buf[cur]
  }
  // epilogue: bias + GLU, write z[m][o] fp32, o in [N0, N0+64)
  const int col = lane & 15, rquad = (lane >> 4) * 4;
#pragma unroll
  for (int j = 0; j < 2; ++j) {
    int o = N0 + wn + 16 * j + col;
    float ba = bias[o];
    float bg = bias[512 + o];
#pragma unroll
    for (int i = 0; i < 4; ++i) {
      int mbase = M0 + wm + 16 * i + rquad;
#pragma unroll
      for (int rg = 0; rg < 4; ++rg) {
        float a = acc_a[i][j][rg] + ba;
        float g = acc_g[i][j][rg] + bg;
        float zv = a * __frcp_rn(1.f + __expf(-g));
        z[(size_t)(mbase + rg) * 512 + o] = zv;
      }
    }
  }
}

// ---------------- K5: LayerNorm over 512 (in-place on d_out) ------------
__global__ __launch_bounds__(256) void k_ln(
    float* __restrict__ z, const float* __restrict__ gamma,
    const float* __restrict__ beta) {
  const int m = blockIdx.x * 4 + (threadIdx.x >> 6);
  const int lane = threadIdx.x & 63;
  float* zp = z + (size_t)m * 512;
  float v[8], s = 0.f, sq = 0.f;
#pragma unroll
  for (int j = 0; j < 8; ++j) {
    v[j] = zp[j * 64 + lane];
    s += v[j];
    sq = fmaf(v[j], v[j], sq);
  }
#pragma unroll
  for (int off = 32; off > 0; off >>= 1) {
    s += __shfl_xor(s, off);
    sq += __shfl_xor(sq, off);
  }
  float mean = s * (1.f / 512.f);
  float var = fmaf(-mean, mean, sq * (1.f / 512.f));
  float inv = rsqrtf(var + 1e-5f);
#pragma unroll
  for (int j = 0; j < 8; ++j) {
    int cidx = j * 64 + lane;
    float g = gamma[cidx], be = beta[cidx];
    zp[cidx] = fmaf((v[j] - mean) * inv, g, be);
  }
}

extern "C" void kernel_launch(void* const* d_in, const int* in_sizes, int n_in,
                              void* d_out, int out_size, void* d_ws, size_t ws_size,
                              hipStream_t stream) {
  const float* x      = (const float*)d_in[0];
  const float* ldt_fw = (const float*)d_in[1];
  const float* lar_fw = (const float*)d_in[2];
  const float* ai_fw  = (const float*)d_in[3];
  const float* C_fw   = (const float*)d_in[4];
  const float* ldt_bw = (const float*)d_in[5];
  const float* lar_bw = (const float*)d_in[6];
  const float* ai_bw  = (const float*)d_in[7];
  const float* C_bw   = (const float*)d_in[8];
  const float* Dskip  = (const float*)d_in[9];
  const float* W      = (const float*)d_in[10];
  const float* bias   = (const float*)d_in[11];
  const float* gamma  = (const float*)d_in[12];
  const float* beta   = (const float*)d_in[13];
  float* out = (float*)d_out;

  // workspace map (bytes):
  //  [0)          ActT   512*65536*2  = 67,108,864
  //  [67108864)   SlocT  16*2*16*256*64*4 = 33,554,432
  //  [100663296)  x16    256*65536*2  = 33,554,432
  //  [134217728)  Vm     2*256*64*256*2 = 16,777,216
  //  [150994944)  P      2*256*256*64*2 = 16,777,216
  //  [167772160)  KK     2*256*512*2  = 524,288
  //  [168296448)  wtb    2*256*64*4   = 131,072
  //  [168427520)  Wb     1,048,576     -> total ~169.5 MB
  //  Act (final [m][ch], 67,108,864 B) aliases [SlocT + x16]; both dead by k_tr2.
  char* wsb = (char*)d_ws;
  bf16*     ActT  = (bf16*)wsb;
  float*    SlocT = (float*)(wsb + 67108864u);
  _Float16* x16   = (_Float16*)(wsb + 100663296u);
  _Float16* Vm    = (_Float16*)(wsb + 134217728u);
  _Float16* P     = (_Float16*)(wsb + 150994944u);
  _Float16* KK    = (_Float16*)(wsb + 167772160u);
  float*    wtb   = (float*)(wsb + 168296448u);
  bf16*     Wb    = (bf16*)(wsb + 168427520u);
  bf16*     Act   = (bf16*)(wsb + 67108864u);   // alias over SlocT+x16

  k_prep<<<dim3(256, 2), dim3(64), 0, stream>>>(
      ldt_fw, lar_fw, ai_fw, C_fw, ldt_bw, lar_bw, ai_bw, C_bw, Vm, P, KK, wtb);
  k_wconv<<<dim3(2048), dim3(256), 0, stream>>>(W, Wb, 1024 * 512);
  k_tr<<<dim3(Mtot / 64, 4), dim3(256), 0, stream>>>(x, x16);
  k_mm1<<<dim3(256, 2), dim3(256), 0, stream>>>(x16, Vm, SlocT);
  k_scan2<<<dim3(Bsz, 2, 4), dim3(256), 0, stream>>>(wtb, SlocT);
  k_mm2<<<dim3(256, 2), dim3(512), 0, stream>>>(x16, KK, P, SlocT, Dskip, ActT);
  k_tr2<<<dim3(Mtot / 64, 8), dim3(256), 0, stream>>>(ActT, Act);
  k_gemm<<<dim3(4096), dim3(256), 0, stream>>>(Act, Wb, bias, out);
  k_ln<<<dim3(Mtot / 4), dim3(256), 0, stream>>>(out, gamma, beta);
}